// Round 1
// baseline (574.456 us; speedup 1.0000x reference)
//
#include <hip/hip_runtime.h>
#include <hip/hip_bf16.h>

#define TT 50
#define BB 64
#define SS 100
#define HH 512
#define VT 32000
#define VE 5000
#define LDC 37000          // VT + VE
#define MROWS 3200         // T*B

typedef __bf16 bf16x8 __attribute__((ext_vector_type(8)));
typedef float f32x4 __attribute__((ext_vector_type(4)));

__device__ __forceinline__ ushort f2bf(float f) {
    unsigned u = __float_as_uint(f);
    u += 0x7fffu + ((u >> 16) & 1u);   // RNE
    return (ushort)(u >> 16);
}

// ---------------- pass 0: fp32 -> bf16 conversion of W and hidden ----------------
__global__ void convert_kernel(const float* __restrict__ W, const float* __restrict__ hid,
                               ushort* __restrict__ wsB, ushort* __restrict__ wsA) {
    int g = blockIdx.x * 256 + threadIdx.x;      // 0 .. 4,505,599 float4-groups
    const int WG = 4096000;                      // W float4-groups
    float4 v;
    ushort* dst;
    if (g < WG) {
        v = ((const float4*)W)[g];
        dst = wsB + 4 * (size_t)g;
    } else {
        int h = g - WG;
        v = ((const float4*)hid)[h];
        dst = wsA + 4 * (size_t)h;
    }
    ushort4 o;
    o.x = f2bf(v.x); o.y = f2bf(v.y); o.z = f2bf(v.z); o.w = f2bf(v.w);
    *(ushort4*)dst = o;
}

// ---------------- pass 1: bf16 MFMA GEMM, logits -> d_out (stride LDC) ----------------
// C = A[3200x512] * B^T[32000x512] + bias.  128x128 tile, BK=32, 4 waves (2x2), 4x4 frags.
__global__ void gemm_kernel(const ushort* __restrict__ A, const ushort* __restrict__ B,
                            const float* __restrict__ bias, float* __restrict__ C) {
    __shared__ ushort lds[8192];                 // A: bytes [0,8192), B: [8192,16384)
    const int tid  = threadIdx.x;
    const int w    = tid >> 6;
    const int lane = tid & 63;
    const int wr   = w >> 1, wc = w & 1;
    const int brow = blockIdx.y * 128;
    const int bcol = blockIdx.x * 128;
    const int lr   = lane & 15;                  // fragment row/col
    const int kg   = lane >> 4;                  // k-group 0..3

    char* ldsAb = (char*)lds;
    char* ldsBb = (char*)lds + 8192;

    f32x4 acc[4][4];
#pragma unroll
    for (int m = 0; m < 4; ++m)
#pragma unroll
        for (int n = 0; n < 4; ++n)
            acc[m][n] = (f32x4){0.f, 0.f, 0.f, 0.f};

    for (int kt = 0; kt < 16; ++kt) {
        __syncthreads();                         // prev compute done before overwrite
#pragma unroll
        for (int j = 0; j < 2; ++j) {
            int c = tid + j * 256;               // chunk id 0..511
            int row = c >> 2, kc = c & 3;
            const ushort* srcA = A + (size_t)(brow + row) * HH + kt * 32 + kc * 8;
            __builtin_amdgcn_global_load_lds(
                (const __attribute__((address_space(1))) void*)srcA,
                (__attribute__((address_space(3))) void*)(ldsAb + (w * 64 + j * 256) * 16),
                16, 0, 0);
            const ushort* srcB = B + (size_t)(bcol + row) * HH + kt * 32 + kc * 8;
            __builtin_amdgcn_global_load_lds(
                (const __attribute__((address_space(1))) void*)srcB,
                (__attribute__((address_space(3))) void*)(ldsBb + (w * 64 + j * 256) * 16),
                16, 0, 0);
        }
        __syncthreads();                         // compiler drains vmcnt before barrier

        bf16x8 af[4], bfr[4];
#pragma unroll
        for (int m = 0; m < 4; ++m)
            af[m] = *(const bf16x8*)(ldsAb + ((wr * 64 + m * 16 + lr) * 64 + kg * 16));
#pragma unroll
        for (int n = 0; n < 4; ++n)
            bfr[n] = *(const bf16x8*)(ldsBb + ((wc * 64 + n * 16 + lr) * 64 + kg * 16));
#pragma unroll
        for (int m = 0; m < 4; ++m)
#pragma unroll
            for (int n = 0; n < 4; ++n)
                acc[m][n] = __builtin_amdgcn_mfma_f32_16x16x32_bf16(af[m], bfr[n], acc[m][n], 0, 0, 0);
    }

    // epilogue: C[row][col], col = lane&15, row = (lane>>4)*4 + reg   [m89 layout]
#pragma unroll
    for (int n = 0; n < 4; ++n) {
        int col = bcol + wc * 64 + n * 16 + lr;
        float bv = bias[col];
#pragma unroll
        for (int m = 0; m < 4; ++m) {
            int row0 = brow + wr * 64 + m * 16 + kg * 4;
#pragma unroll
            for (int r = 0; r < 4; ++r)
                C[(size_t)(row0 + r) * LDC + col] = acc[m][n][r] + bv;
        }
    }
}

// ---------------- pass 2: per-row online logsumexp over VT logits ----------------
__global__ void lse_kernel(const float* __restrict__ out, float* __restrict__ lse) {
    int r = blockIdx.x;
    int t = threadIdx.x;
    const float4* p = (const float4*)(out + (size_t)r * LDC);
    float m = -1e30f, s = 0.f;
    for (int i = t; i < VT / 4; i += 256) {
        float4 v = p[i];
        float mx = fmaxf(fmaxf(v.x, v.y), fmaxf(v.z, v.w));
        float nm = fmaxf(m, mx);
        s = s * __expf(m - nm) + __expf(v.x - nm) + __expf(v.y - nm)
                               + __expf(v.z - nm) + __expf(v.w - nm);
        m = nm;
    }
    for (int off = 1; off < 64; off <<= 1) {
        float om = __shfl_xor(m, off);
        float os = __shfl_xor(s, off);
        float nm = fmaxf(m, om);
        s = s * __expf(m - nm) + os * __expf(om - nm);
        m = nm;
    }
    __shared__ float sm[4], ss[4];
    int w = t >> 6, lane = t & 63;
    if (lane == 0) { sm[w] = m; ss[w] = s; }
    __syncthreads();
    if (t == 0) {
        float M = sm[0], S = ss[0];
        for (int i = 1; i < 4; ++i) {
            float nm = fmaxf(M, sm[i]);
            S = S * __expf(M - nm) + ss[i] * __expf(sm[i] - nm);
            M = nm;
        }
        lse[r] = M + __logf(S);
    }
}

// ---------------- pass 3: gate + normalize + ext scatter + safe_log ----------------
__global__ void finish_kernel(float* __restrict__ out, const float* __restrict__ lse,
                              const float* __restrict__ dec, const float* __restrict__ wc,
                              const float* __restrict__ bcp, const float* __restrict__ attn,
                              const int* __restrict__ cte) {
    int r = blockIdx.x;          // t*B + b
    int t = threadIdx.x;
    __shared__ float red[4];
    __shared__ float cshare;
    __shared__ float bins[VE];

    // copy gate: sigmoid(dot(dec[r], Wc) + bc)
    const float* d = dec + (size_t)r * HH;
    float part = d[t] * wc[t] + d[t + 256] * wc[t + 256];
    for (int off = 1; off < 64; off <<= 1) part += __shfl_xor(part, off);
    int w = t >> 6, lane = t & 63;
    if (lane == 0) red[w] = part;
    __syncthreads();
    if (t == 0) {
        float g = red[0] + red[1] + red[2] + red[3] + bcp[0];
        cshare = 1.f / (1.f + __expf(-g));
    }
    for (int v = t; v < VE; v += 256) bins[v] = 0.f;
    __syncthreads();
    float c = cshare;

    // normalize log-softmax region in-place
    float l = lse[r];
    float4* p = (float4*)(out + (size_t)r * LDC);
    for (int i = t; i < VT / 4; i += 256) {
        float4 v = p[i];
        v.x -= l; v.y -= l; v.z -= l; v.w -= l;
        p[i] = v;
    }

    // masked scatter of attn mass into ext bins
    if (t < SS) {
        float aw = attn[(size_t)r * SS + t] * (1.f - c);
        int idx = cte[t * BB + (r & 63)];      // copy_to_ext[s][b]
        if (idx != 0) atomicAdd(&bins[idx], aw);
    }
    __syncthreads();

    float* eo = out + (size_t)r * LDC + VT;
    for (int v = t; v < VE; v += 256) {
        float x = fminf(fmaxf(bins[v], 0.001f), 0.999f);
        eo[v] = __logf(x);
    }
}

extern "C" void kernel_launch(void* const* d_in, const int* in_sizes, int n_in,
                              void* d_out, int out_size, void* d_ws, size_t ws_size,
                              hipStream_t stream) {
    const float* hidden = (const float*)d_in[0];
    const float* dec    = (const float*)d_in[1];
    // d_in[2] = concat_c, unused by the reference
    const float* attn   = (const float*)d_in[3];
    const int*   cte    = (const int*)d_in[4];
    const float* W      = (const float*)d_in[5];
    const float* bias   = (const float*)d_in[6];
    const float* Wc     = (const float*)d_in[7];
    const float* bc     = (const float*)d_in[8];
    float* out = (float*)d_out;

    ushort* wsB = (ushort*)d_ws;             // W  bf16 [32000][512]  (32.77 MB)
    ushort* wsA = wsB + (size_t)VT * HH;     // hidden bf16 [3200][512] (3.28 MB)
    float*  wsL = (float*)(wsA + (size_t)MROWS * HH);  // lse [3200]

    convert_kernel<<<17600, 256, 0, stream>>>(W, hidden, wsB, wsA);
    gemm_kernel<<<dim3(250, 25), 256, 0, stream>>>(wsA, wsB, bias, out);
    lse_kernel<<<MROWS, 256, 0, stream>>>(out, wsL);
    finish_kernel<<<MROWS, 256, 0, stream>>>(out, wsL, dec, Wc, bc, attn, cte);
}

// Round 2
// 368.761 us; speedup vs baseline: 1.5578x; 1.5578x over previous
//
#include <hip/hip_runtime.h>
#include <hip/hip_bf16.h>

#define TT 50
#define BB 64
#define SS 100
#define HH 512
#define VT 32000
#define VE 5000
#define LDC 37000          // VT + VE
#define MROWS 3200         // T*B
#define NTILE 250          // VT/128
#define TSTR 136           // padded LDS tile stride (ushorts)

typedef __bf16 bf16x8 __attribute__((ext_vector_type(8)));
typedef float f32x4 __attribute__((ext_vector_type(4)));

__device__ __forceinline__ ushort f2bf(float f) {
    unsigned u = __float_as_uint(f);
    u += 0x7fffu + ((u >> 16) & 1u);   // RNE
    return (ushort)(u >> 16);
}
__device__ __forceinline__ float bflo(unsigned u) { return __uint_as_float(u << 16); }
__device__ __forceinline__ float bfhi(unsigned u) { return __uint_as_float(u & 0xffff0000u); }

// ---------------- pass 0: fp32 -> bf16 conversion of W and hidden ----------------
__global__ void convert_kernel(const float* __restrict__ W, const float* __restrict__ hid,
                               ushort* __restrict__ wsB, ushort* __restrict__ wsA) {
    int g = blockIdx.x * 256 + threadIdx.x;
    const int WG = 4096000;                      // W float4-groups
    float4 v;
    ushort* dst;
    if (g < WG) {
        v = ((const float4*)W)[g];
        dst = wsB + 4 * (size_t)g;
    } else {
        int h = g - WG;
        v = ((const float4*)hid)[h];
        dst = wsA + 4 * (size_t)h;
    }
    ushort4 o;
    o.x = f2bf(v.x); o.y = f2bf(v.y); o.z = f2bf(v.z); o.w = f2bf(v.w);
    *(ushort4*)dst = o;
}

// ---------------- pass 1: bf16 MFMA GEMM ----------------
// C = A[3200x512] * B^T[32000x512] + bias.
// Stores bf16 logits into the TAIL 64000B of each output row (out is fp32 [3200][37000];
// row r's bf16 logits live at ushort offset r*74000 + 42000). Also emits per-(tile,row)
// online-softmax partials (max, sumexp) to pm/ps.
__global__ void gemm_kernel(const ushort* __restrict__ A, const ushort* __restrict__ B,
                            const float* __restrict__ bias, ushort* __restrict__ outu,
                            float* __restrict__ pm, float* __restrict__ ps) {
    __shared__ ushort lds[8192];                 // A: bytes [0,8192), B: [8192,16384)
    __shared__ ushort tileT[128 * TSTR];         // bf16 output tile, padded
    const int tid  = threadIdx.x;
    const int w    = tid >> 6;
    const int lane = tid & 63;
    const int wr   = w >> 1, wc = w & 1;
    const int brow = blockIdx.y * 128;
    const int bcol = blockIdx.x * 128;
    const int lr   = lane & 15;
    const int kg   = lane >> 4;

    char* ldsAb = (char*)lds;
    char* ldsBb = (char*)lds + 8192;

    f32x4 acc[4][4];
#pragma unroll
    for (int m = 0; m < 4; ++m)
#pragma unroll
        for (int n = 0; n < 4; ++n)
            acc[m][n] = (f32x4){0.f, 0.f, 0.f, 0.f};

    for (int kt = 0; kt < 16; ++kt) {
        __syncthreads();
#pragma unroll
        for (int j = 0; j < 2; ++j) {
            int c = tid + j * 256;
            int row = c >> 2, kc = c & 3;
            const ushort* srcA = A + (size_t)(brow + row) * HH + kt * 32 + kc * 8;
            __builtin_amdgcn_global_load_lds(
                (const __attribute__((address_space(1))) void*)srcA,
                (__attribute__((address_space(3))) void*)(ldsAb + (w * 64 + j * 256) * 16),
                16, 0, 0);
            const ushort* srcB = B + (size_t)(bcol + row) * HH + kt * 32 + kc * 8;
            __builtin_amdgcn_global_load_lds(
                (const __attribute__((address_space(1))) void*)srcB,
                (__attribute__((address_space(3))) void*)(ldsBb + (w * 64 + j * 256) * 16),
                16, 0, 0);
        }
        __syncthreads();

        bf16x8 af[4], bfr[4];
#pragma unroll
        for (int m = 0; m < 4; ++m)
            af[m] = *(const bf16x8*)(ldsAb + ((wr * 64 + m * 16 + lr) * 64 + kg * 16));
#pragma unroll
        for (int n = 0; n < 4; ++n)
            bfr[n] = *(const bf16x8*)(ldsBb + ((wc * 64 + n * 16 + lr) * 64 + kg * 16));
#pragma unroll
        for (int m = 0; m < 4; ++m)
#pragma unroll
            for (int n = 0; n < 4; ++n)
                acc[m][n] = __builtin_amdgcn_mfma_f32_16x16x32_bf16(af[m], bfr[n], acc[m][n], 0, 0, 0);
    }

    // ---- epilogue: acc (+bias) -> bf16 LDS tile ----
#pragma unroll
    for (int n = 0; n < 4; ++n) {
        int col = wc * 64 + n * 16 + lr;
        float bv = bias[bcol + col];
#pragma unroll
        for (int m = 0; m < 4; ++m) {
            int row0 = wr * 64 + m * 16 + kg * 4;
#pragma unroll
            for (int r = 0; r < 4; ++r)
                tileT[(row0 + r) * TSTR + col] = f2bf(acc[m][n][r] + bv);
        }
    }
    __syncthreads();

    // ---- coalesced bf16 store to out-row tails (256B segments) ----
#pragma unroll
    for (int it = 0; it < 8; ++it) {
        int idx = it * 256 + tid;
        int row = idx >> 4, ch = idx & 15;
        uint4 v = *(const uint4*)(&tileT[row * TSTR + ch * 8]);
        *(uint4*)(outu + (size_t)(brow + row) * 74000 + 42000 + bcol + ch * 8) = v;
    }

    // ---- per-row partial (max, sumexp) over this tile's 128 cols ----
    {
        int prow = tid >> 1, half = tid & 1;
        const ushort* trow = &tileT[prow * TSTR + half * 64];
        uint4 vv[8];
#pragma unroll
        for (int i = 0; i < 8; ++i) vv[i] = *(const uint4*)(trow + i * 8);
        float mx = -1e30f;
#pragma unroll
        for (int i = 0; i < 8; ++i) {
            mx = fmaxf(mx, fmaxf(fmaxf(bflo(vv[i].x), bfhi(vv[i].x)), fmaxf(bflo(vv[i].y), bfhi(vv[i].y))));
            mx = fmaxf(mx, fmaxf(fmaxf(bflo(vv[i].z), bfhi(vv[i].z)), fmaxf(bflo(vv[i].w), bfhi(vv[i].w))));
        }
        float sx = 0.f;
#pragma unroll
        for (int i = 0; i < 8; ++i) {
            sx += __expf(bflo(vv[i].x) - mx) + __expf(bfhi(vv[i].x) - mx)
                + __expf(bflo(vv[i].y) - mx) + __expf(bfhi(vv[i].y) - mx)
                + __expf(bflo(vv[i].z) - mx) + __expf(bfhi(vv[i].z) - mx)
                + __expf(bflo(vv[i].w) - mx) + __expf(bfhi(vv[i].w) - mx);
        }
        float om = __shfl_xor(mx, 1), os = __shfl_xor(sx, 1);
        float M = fmaxf(mx, om);
        float S = sx * __expf(mx - M) + os * __expf(om - M);
        if (half == 0) {
            pm[(size_t)blockIdx.x * MROWS + brow + prow] = M;
            ps[(size_t)blockIdx.x * MROWS + brow + prow] = S;
        }
    }
}

// ---------------- pass 2: reduce partials -> lse; normalize row to fp32 ----------------
// One block per row. Stages the row's bf16 logits (out tail) into LDS, then overwrites
// the row with fp32 log-softmax. Safe: single owner of the row; tail cols >=22000 are
// only clobbered later by ext_kernel (separate dispatch).
__global__ __launch_bounds__(512) void norm_kernel(float* __restrict__ out,
                                                   const float* __restrict__ pm,
                                                   const float* __restrict__ ps) {
    const int r = blockIdx.x;
    const int t = threadIdx.x;
    __shared__ float sm[8], ssum[8];
    __shared__ float lse_sh;
    __shared__ ushort rowbuf[VT];                // 64000 B

    float m = -1e30f, s = 0.f;
    if (t < NTILE) {
        m = pm[(size_t)t * MROWS + r];
        s = ps[(size_t)t * MROWS + r];
    }
    for (int off = 1; off < 64; off <<= 1) {
        float om = __shfl_xor(m, off), os = __shfl_xor(s, off);
        float nm = fmaxf(m, om);
        s = s * __expf(m - nm) + os * __expf(om - nm);
        m = nm;
    }
    int w = t >> 6, lane = t & 63;
    if (lane == 0) { sm[w] = m; ssum[w] = s; }

    // stage bf16 row from out tail into LDS
    const uint4* src = (const uint4*)((const ushort*)out + (size_t)r * 74000 + 42000);
    uint4* dstl = (uint4*)rowbuf;
    for (int i = t; i < VT / 8; i += 512) dstl[i] = src[i];
    __syncthreads();

    if (t == 0) {
        float M = sm[0], S = ssum[0];
        for (int i = 1; i < 8; ++i) {
            float nm = fmaxf(M, sm[i]);
            S = S * __expf(M - nm) + ssum[i] * __expf(sm[i] - nm);
            M = nm;
        }
        lse_sh = M + __logf(S);
    }
    __syncthreads();
    const float l = lse_sh;

    float4* orow = (float4*)(out + (size_t)r * LDC);
    for (int i = t; i < VT / 8; i += 512) {
        uint4 v = dstl[i];
        float4 a, b;
        a.x = bflo(v.x) - l; a.y = bfhi(v.x) - l;
        a.z = bflo(v.y) - l; a.w = bfhi(v.y) - l;
        b.x = bflo(v.z) - l; b.y = bfhi(v.z) - l;
        b.z = bflo(v.w) - l; b.w = bfhi(v.w) - l;
        orow[2 * i]     = a;
        orow[2 * i + 1] = b;
    }
}

// ---------------- pass 3: gate + ext scatter + safe_log ----------------
__global__ void ext_kernel(float* __restrict__ out, const float* __restrict__ dec,
                           const float* __restrict__ wc, const float* __restrict__ bcp,
                           const float* __restrict__ attn, const int* __restrict__ cte) {
    const int r = blockIdx.x;
    const int t = threadIdx.x;
    __shared__ float red[4];
    __shared__ float cshare;
    __shared__ float bins[VE];

    const float* d = dec + (size_t)r * HH;
    float part = d[t] * wc[t] + d[t + 256] * wc[t + 256];
    for (int off = 1; off < 64; off <<= 1) part += __shfl_xor(part, off);
    int w = t >> 6, lane = t & 63;
    if (lane == 0) red[w] = part;
    for (int v = t; v < VE; v += 256) bins[v] = 0.f;
    __syncthreads();
    if (t == 0) {
        float g = red[0] + red[1] + red[2] + red[3] + bcp[0];
        cshare = 1.f / (1.f + __expf(-g));
    }
    __syncthreads();
    float c = cshare;

    if (t < SS) {
        float aw = attn[(size_t)r * SS + t] * (1.f - c);
        int idx = cte[t * BB + (r & 63)];
        if (idx != 0) atomicAdd(&bins[idx], aw);
    }
    __syncthreads();

    float4* eo = (float4*)(out + (size_t)r * LDC + VT);
    for (int v = t; v < VE / 4; v += 256) {
        float4 x;
        x.x = __logf(fminf(fmaxf(bins[4 * v + 0], 0.001f), 0.999f));
        x.y = __logf(fminf(fmaxf(bins[4 * v + 1], 0.001f), 0.999f));
        x.z = __logf(fminf(fmaxf(bins[4 * v + 2], 0.001f), 0.999f));
        x.w = __logf(fminf(fmaxf(bins[4 * v + 3], 0.001f), 0.999f));
        eo[v] = x;
    }
}

extern "C" void kernel_launch(void* const* d_in, const int* in_sizes, int n_in,
                              void* d_out, int out_size, void* d_ws, size_t ws_size,
                              hipStream_t stream) {
    const float* hidden = (const float*)d_in[0];
    const float* dec    = (const float*)d_in[1];
    // d_in[2] = concat_c, unused by the reference
    const float* attn   = (const float*)d_in[3];
    const int*   cte    = (const int*)d_in[4];
    const float* W      = (const float*)d_in[5];
    const float* bias   = (const float*)d_in[6];
    const float* Wc     = (const float*)d_in[7];
    const float* bc     = (const float*)d_in[8];
    float* out = (float*)d_out;

    ushort* wsB = (ushort*)d_ws;                       // W bf16  [32000][512]  32.77 MB
    ushort* wsA = wsB + (size_t)VT * HH;               // hidden bf16 [3200][512] 3.28 MB
    float*  pm  = (float*)(wsA + (size_t)MROWS * HH);  // partial max [250][3200] 3.2 MB
    float*  ps  = pm + (size_t)NTILE * MROWS;          // partial sum [250][3200] 3.2 MB

    convert_kernel<<<17600, 256, 0, stream>>>(W, hidden, wsB, wsA);
    gemm_kernel<<<dim3(NTILE, 25), 256, 0, stream>>>(wsA, wsB, bias, (ushort*)out, pm, ps);
    norm_kernel<<<MROWS, 512, 0, stream>>>(out, pm, ps);
    ext_kernel<<<MROWS, 256, 0, stream>>>(out, dec, Wc, bc, attn, cte);
}